// Round 1
// 72.463 us; speedup vs baseline: 1.0004x; 1.0004x over previous
//
#include <hip/hip_runtime.h>

#define SEQ 512
// alpha = log2(e)/sqrt(8); Q pre-scaled by sqrt(alpha) so score = exp2(q'.q')
#define SQRT_ALPHA     0.71419163f
#define INV_SQRT_ALPHA 1.40018452f

typedef float v2f __attribute__((ext_vector_type(2)));

__device__ __forceinline__ v2f pk_fma(v2f a, v2f b, v2f c) {
    return __builtin_elementwise_fma(a, b, c);   // forces v_pk_fma_f32
}

// Kernel 1: analytic quantum feature + attention per (b,h) pair.
// exp[0] = prod_{1..7} cos(x_w+th_w); exp[k] = prod_{0..k} cos(x_w+th_w)
// grid (64 pairs, 8 chunks of 64 rows), block 512 = 8 waves.
// Wave wv owns j-slice [64wv, 64wv+64); the two half-waves take different j
// (2 distinct LDS addrs/instr = free 2-way); each lane holds 2 rows in regs.
__global__ __launch_bounds__(512) void qattn_kernel(
    const float* __restrict__ x,      // fp32 [8,512,64]
    const float* __restrict__ theta,  // fp32 [8]
    float* __restrict__ ctx)          // fp32 [4096][64]
{
    __shared__ float Qs[SEQ][8];      // 16 KB, pre-scaled by SQRT_ALPHA
    __shared__ float red[8][64][9];   // 18 KB, stride-9 conflict-free

    const int pair  = blockIdx.x;     // b*8 + h
    const int chunk = blockIdx.y;     // 0..7 -> rows [64*chunk, +64)
    const int b = pair >> 3, h = pair & 7;
    const int tid = threadIdx.x;

    float th[8];
    #pragma unroll
    for (int w = 0; w < 8; w++) th[w] = theta[w];

    // Build scaled Q: one row per thread
    {
        const int s = tid;
        const float* xp = x + ((size_t)(b * SEQ + s) * 64 + h * 8);
        float4 xa = *reinterpret_cast<const float4*>(xp);
        float4 xb = *reinterpret_cast<const float4*>(xp + 4);
        float c[8];
        c[0] = __cosf(xa.x + th[0]); c[1] = __cosf(xa.y + th[1]);
        c[2] = __cosf(xa.z + th[2]); c[3] = __cosf(xa.w + th[3]);
        c[4] = __cosf(xb.x + th[4]); c[5] = __cosf(xb.y + th[5]);
        c[6] = __cosf(xb.z + th[6]); c[7] = __cosf(xb.w + th[7]);
        float q[8];
        float pre = c[0];
        #pragma unroll
        for (int k = 1; k < 8; k++) { pre *= c[k]; q[k] = pre; }
        float suf = 1.f;
        #pragma unroll
        for (int w = 7; w >= 1; w--) suf *= c[w];
        q[0] = suf;
        float4 qa = make_float4(q[0]*SQRT_ALPHA, q[1]*SQRT_ALPHA, q[2]*SQRT_ALPHA, q[3]*SQRT_ALPHA);
        float4 qb = make_float4(q[4]*SQRT_ALPHA, q[5]*SQRT_ALPHA, q[6]*SQRT_ALPHA, q[7]*SQRT_ALPHA);
        *reinterpret_cast<float4*>(&Qs[s][0]) = qa;
        *reinterpret_cast<float4*>(&Qs[s][4]) = qb;
    }
    __syncthreads();

    const int lane = tid & 63;
    const int wv   = tid >> 6;        // 0..7
    const int L    = lane & 31;       // row-set index; rows L + {0,32}

    // 2 rows of Q in registers
    v2f q01[2], q23[2], q45[2], q67[2];
    #pragma unroll
    for (int k = 0; k < 2; k++) {
        const float* qp = &Qs[chunk * 64 + 32 * k + L][0];
        q01[k] = *reinterpret_cast<const v2f*>(qp + 0);
        q23[k] = *reinterpret_cast<const v2f*>(qp + 2);
        q45[k] = *reinterpret_cast<const v2f*>(qp + 4);
        q67[k] = *reinterpret_cast<const v2f*>(qp + 6);
    }

    v2f a01[2], a23[2], a45[2], a67[2];
    float l[2];
    #pragma unroll
    for (int k = 0; k < 2; k++) {
        a01[k] = (v2f){0.f, 0.f}; a23[k] = a01[k];
        a45[k] = a01[k]; a67[k] = a01[k]; l[k] = 0.f;
    }

    // |q'.q'| <= 8*alpha = 4.08: exp2 safe without max-subtraction
    const float* up = &Qs[wv * 64 + 32 * (lane >> 5)][0];
    #pragma unroll 8
    for (int i = 0; i < 32; i++) {
        v2f u0 = *reinterpret_cast<const v2f*>(up + i * 8 + 0);
        v2f u1 = *reinterpret_cast<const v2f*>(up + i * 8 + 2);
        v2f u2 = *reinterpret_cast<const v2f*>(up + i * 8 + 4);
        v2f u3 = *reinterpret_cast<const v2f*>(up + i * 8 + 6);
        #pragma unroll
        for (int k = 0; k < 2; k++) {
            v2f d = pk_fma(q01[k], u0, pk_fma(q23[k], u1, pk_fma(q45[k], u2,
                    q67[k] * u3)));
            float e = __builtin_amdgcn_exp2f(d.x + d.y);
            l[k] += e;
            v2f ev = {e, e};
            a01[k] = pk_fma(ev, u0, a01[k]); a23[k] = pk_fma(ev, u1, a23[k]);
            a45[k] = pk_fma(ev, u2, a45[k]); a67[k] = pk_fma(ev, u3, a67[k]);
        }
    }

    // merge the two j-halves (lane ^ 32)
    #pragma unroll
    for (int k = 0; k < 2; k++) {
        a01[k].x += __shfl_xor(a01[k].x, 32); a01[k].y += __shfl_xor(a01[k].y, 32);
        a23[k].x += __shfl_xor(a23[k].x, 32); a23[k].y += __shfl_xor(a23[k].y, 32);
        a45[k].x += __shfl_xor(a45[k].x, 32); a45[k].y += __shfl_xor(a45[k].y, 32);
        a67[k].x += __shfl_xor(a67[k].x, 32); a67[k].y += __shfl_xor(a67[k].y, 32);
        l[k]     += __shfl_xor(l[k], 32);
    }

    if (lane < 32) {
        #pragma unroll
        for (int k = 0; k < 2; k++) {
            float* rp = &red[wv][32 * k + L][0];
            rp[0] = a01[k].x; rp[1] = a01[k].y; rp[2] = a23[k].x; rp[3] = a23[k].y;
            rp[4] = a45[k].x; rp[5] = a45[k].y; rp[6] = a67[k].x; rp[7] = a67[k].y;
            rp[8] = l[k];
        }
    }
    __syncthreads();

    // final reduce over 8 waves: 512 (row,d) items over 512 threads
    {
        int lr = tid >> 3, d = tid & 7;
        float v = 0.f, ll = 0.f;
        #pragma unroll
        for (int w = 0; w < 8; w++) { v += red[w][lr][d]; ll += red[w][lr][8]; }
        int row = chunk * 64 + lr;
        ctx[(size_t)(b * SEQ + row) * 64 + h * 8 + d] = v * INV_SQRT_ALPHA / ll;
    }
}

// Kernel 2: out[t, e] = ctx[t, :] . W_o[e, :] + b_o[e]
// grid 512 x 256; wave handles 2 tokens (all 64 e per token)
__global__ __launch_bounds__(256) void proj_kernel(
    const float* __restrict__ ctx,    // fp32 [4096][64]
    const float* __restrict__ Wo,     // fp32 [64][64]
    const float* __restrict__ bo,     // fp32 [64]
    float* __restrict__ out)          // fp32 [4096][64]
{
    __shared__ float Ws[64][68];      // pitch 68: 16B-aligned rows, conflict-free b128
    const int tid = threadIdx.x;
    #pragma unroll
    for (int i = 0; i < 16; i++) {
        int idx = i * 256 + tid;
        Ws[idx >> 6][idx & 63] = Wo[idx];
    }
    __syncthreads();

    const int e  = tid & 63;
    const int tg = tid >> 6;
    const int t0 = blockIdx.x * 8 + tg * 2;

    const float4* c0 = reinterpret_cast<const float4*>(ctx + (size_t)t0 * 64);
    const float4* c1 = reinterpret_cast<const float4*>(ctx + (size_t)(t0 + 1) * 64);
    float a0 = 0.f, a1 = 0.f;
    #pragma unroll 4
    for (int k4 = 0; k4 < 16; k4++) {
        float4 w  = *reinterpret_cast<const float4*>(&Ws[e][k4 * 4]);
        float4 x0 = c0[k4];            // wave-uniform broadcast
        float4 x1 = c1[k4];
        a0 += x0.x*w.x + x0.y*w.y + x0.z*w.z + x0.w*w.w;
        a1 += x1.x*w.x + x1.y*w.y + x1.z*w.z + x1.w*w.w;
    }
    float bb = bo[e];
    out[(size_t)t0 * 64 + e]       = a0 + bb;
    out[(size_t)(t0 + 1) * 64 + e] = a1 + bb;
}

extern "C" void kernel_launch(void* const* d_in, const int* in_sizes, int n_in,
                              void* d_out, int out_size, void* d_ws, size_t ws_size,
                              hipStream_t stream) {
    const float* x     = (const float*)d_in[0];  // [8,512,64]
    const float* theta = (const float*)d_in[1];  // [8]
    const float* Wo    = (const float*)d_in[2];  // [64,64]
    const float* bo    = (const float*)d_in[3];  // [64]
    float* out = (float*)d_out;                  // [8,512,64]
    float* ctx = (float*)d_ws;                   // 1 MB fp32 scratch

    qattn_kernel<<<dim3(64, 8), 512, 0, stream>>>(x, theta, ctx);
    proj_kernel<<<512, 256, 0, stream>>>(ctx, Wo, bo, out);
}

// Round 3
// 67.347 us; speedup vs baseline: 1.0763x; 1.0759x over previous
//
#include <hip/hip_runtime.h>

#define SEQ 512
// alpha = log2(e)/sqrt(8); Q pre-scaled by sqrt(alpha) so score = exp2(q'.q')
#define SQRT_ALPHA     0.71419163f
#define INV_SQRT_ALPHA 1.40018452f

typedef _Float16 half4 __attribute__((ext_vector_type(4)));
typedef _Float16 half2t __attribute__((ext_vector_type(2)));
typedef float f32x4 __attribute__((ext_vector_type(4)));

// LDS strides in u16 units, chosen for bank spread + 8B alignment of b64 reads
#define QS_STRIDE 20    // 16 k-cols (8 data + 8 zeros for K=16 pad) + 4 pad
#define QT_STRIDE 524   // 512 t + 12 pad (stride*2 % 8 == 0, banks ~2-way)

// Kernel 1: MFMA quantum attention.
// Scores S = Q'.Q'^T are symmetric, so the D-fragment of mfma(Qfrag_T, Qfrag_R)
// (col=lane&15,row=4*(lane>>4)+reg) reads back EXACTLY as the A-fragment
// (row=lane&15,k=4*(lane>>4)+j) of E for the PV matmul: no shuffles.
// V = [Q' | 1 | 0...]: col 8 accumulates the softmax denominator for free.
// grid (64 pairs, 8), block 256 = 4 waves; wave owns 16-row block R.
__global__ __launch_bounds__(256) void qattn_kernel(
    const float* __restrict__ x,      // fp32 [8,512,64]
    const float* __restrict__ theta,  // fp32 [8]
    float* __restrict__ ctx)          // fp32 [4096][64]
{
    __shared__ unsigned short Q16[SEQ * QS_STRIDE];   // 20480 B, A/B frags
    __shared__ unsigned short QT16[16 * QT_STRIDE];   // 16768 B, V^T (B frags)

    const int pair = blockIdx.x;      // b*8 + h
    const int b = pair >> 3, h = pair & 7;
    const int tid = threadIdx.x;

    float th[8];
    #pragma unroll
    for (int w = 0; w < 8; w++) th[w] = theta[w];

    // Build scaled Q in f16: each thread does rows tid, tid+256
    #pragma unroll
    for (int rr = 0; rr < 2; rr++) {
        const int s = tid + rr * 256;
        const float* xp = x + ((size_t)(b * SEQ + s) * 64 + h * 8);
        float4 xa = *reinterpret_cast<const float4*>(xp);
        float4 xb = *reinterpret_cast<const float4*>(xp + 4);
        float c[8];
        c[0] = __cosf(xa.x + th[0]); c[1] = __cosf(xa.y + th[1]);
        c[2] = __cosf(xa.z + th[2]); c[3] = __cosf(xa.w + th[3]);
        c[4] = __cosf(xb.x + th[4]); c[5] = __cosf(xb.y + th[5]);
        c[6] = __cosf(xb.z + th[6]); c[7] = __cosf(xb.w + th[7]);
        float q[8];
        float pre = c[0];
        #pragma unroll
        for (int k = 1; k < 8; k++) { pre *= c[k]; q[k] = pre; }
        float suf = 1.f;
        #pragma unroll
        for (int w = 7; w >= 1; w--) suf *= c[w];
        q[0] = suf;
        _Float16 qh[8];
        #pragma unroll
        for (int k = 0; k < 8; k++) qh[k] = (_Float16)(q[k] * SQRT_ALPHA);
        // row-major fragment source (k-cols 8..15 zero-padded for K=16)
        half4 lo = {qh[0], qh[1], qh[2], qh[3]};
        half4 hi = {qh[4], qh[5], qh[6], qh[7]};
        *reinterpret_cast<half4*>(&Q16[s * QS_STRIDE + 0])  = lo;
        *reinterpret_cast<half4*>(&Q16[s * QS_STRIDE + 4])  = hi;
        *reinterpret_cast<half4*>(&Q16[s * QS_STRIDE + 8])  = (half4)0;
        *reinterpret_cast<half4*>(&Q16[s * QS_STRIDE + 12]) = (half4)0;
        // transposed V for PV B-fragments: col-major, col 8 = ones
        #pragma unroll
        for (int c8 = 0; c8 < 8; c8++)
            *reinterpret_cast<_Float16*>(&QT16[c8 * QT_STRIDE + s]) = qh[c8];
        *reinterpret_cast<_Float16*>(&QT16[8 * QT_STRIDE + s]) = (_Float16)1.0f;
        #pragma unroll
        for (int c8 = 9; c8 < 16; c8++) QT16[c8 * QT_STRIDE + s] = 0;
    }
    __syncthreads();

    const int lane = tid & 63;
    const int wv   = tid >> 6;            // 0..3
    const int R    = blockIdx.y * 4 + wv; // 16-row block 0..31
    const int lr   = lane & 15;           // col index in fragments
    const int lg   = lane >> 4;           // k/row group

    // loop-invariant B-fragment for scores: rows of Q'-block R (X.X^T trick)
    half4 qb = *reinterpret_cast<const half4*>(
        &Q16[(R * 16 + lr) * QS_STRIDE + lg * 4]);

    const unsigned short* aptr = &Q16[lr * QS_STRIDE + lg * 4];
    const unsigned short* vptr = &QT16[lr * QT_STRIDE + lg * 4];

    f32x4 acc = {0.f, 0.f, 0.f, 0.f};
    #pragma unroll 4
    for (int T = 0; T < 32; T++) {
        half4 qa = *reinterpret_cast<const half4*>(aptr + T * 16 * QS_STRIDE);
        half4 vt = *reinterpret_cast<const half4*>(vptr + T * 16);
        f32x4 sv = __builtin_amdgcn_mfma_f32_16x16x16f16(
            qa, qb, (f32x4){0.f, 0.f, 0.f, 0.f}, 0, 0, 0);
        // |score| <= 8*alpha = 4.08: exp2 safe without max-subtraction
        float e0 = __builtin_amdgcn_exp2f(sv.x);
        float e1 = __builtin_amdgcn_exp2f(sv.y);
        float e2 = __builtin_amdgcn_exp2f(sv.z);
        float e3 = __builtin_amdgcn_exp2f(sv.w);
        half2t p0 = __builtin_bit_cast(half2t, __builtin_amdgcn_cvt_pkrtz(e0, e1));
        half2t p1 = __builtin_bit_cast(half2t, __builtin_amdgcn_cvt_pkrtz(e2, e3));
        half4 ef = {p0.x, p0.y, p1.x, p1.y};  // D-layout == A-layout (S symm)
        acc = __builtin_amdgcn_mfma_f32_16x16x16f16(ef, vt, acc, 0, 0, 0);
    }

    // acc: lane (lg,lr), reg j -> ctx row R*16+lg*4+j, col lr (8 = denom)
    const int src = (lane & 48) | 8;      // denominator lane of this row group
    float res[4];
    #pragma unroll
    for (int j = 0; j < 4; j++) {
        float lv = __shfl(acc[j], src, 64);
        res[j] = acc[j] * (INV_SQRT_ALPHA * __builtin_amdgcn_rcpf(lv));
    }
    if (lr < 8) {
        const int rowb = b * SEQ + R * 16 + lg * 4;
        #pragma unroll
        for (int j = 0; j < 4; j++)
            ctx[(size_t)(rowb + j) * 64 + h * 8 + lr] = res[j];
    }
}

// Kernel 2: out[t, e] = ctx[t, :] . W_o[e, :] + b_o[e]
// grid 512 x 256; wave handles 2 tokens (all 64 e per token)
__global__ __launch_bounds__(256) void proj_kernel(
    const float* __restrict__ ctx,    // fp32 [4096][64]
    const float* __restrict__ Wo,     // fp32 [64][64]
    const float* __restrict__ bo,     // fp32 [64]
    float* __restrict__ out)          // fp32 [4096][64]
{
    __shared__ float Ws[64][68];      // pitch 68: 16B-aligned rows, conflict-free b128
    const int tid = threadIdx.x;
    #pragma unroll
    for (int i = 0; i < 16; i++) {
        int idx = i * 256 + tid;
        Ws[idx >> 6][idx & 63] = Wo[idx];
    }
    __syncthreads();

    const int e  = tid & 63;
    const int tg = tid >> 6;
    const int t0 = blockIdx.x * 8 + tg * 2;

    const float4* c0 = reinterpret_cast<const float4*>(ctx + (size_t)t0 * 64);
    const float4* c1 = reinterpret_cast<const float4*>(ctx + (size_t)(t0 + 1) * 64);
    float a0 = 0.f, a1 = 0.f;
    #pragma unroll 4
    for (int k4 = 0; k4 < 16; k4++) {
        float4 w  = *reinterpret_cast<const float4*>(&Ws[e][k4 * 4]);
        float4 x0 = c0[k4];            // wave-uniform broadcast
        float4 x1 = c1[k4];
        a0 += x0.x*w.x + x0.y*w.y + x0.z*w.z + x0.w*w.w;
        a1 += x1.x*w.x + x1.y*w.y + x1.z*w.z + x1.w*w.w;
    }
    float bb = bo[e];
    out[(size_t)t0 * 64 + e]       = a0 + bb;
    out[(size_t)(t0 + 1) * 64 + e] = a1 + bb;
}

extern "C" void kernel_launch(void* const* d_in, const int* in_sizes, int n_in,
                              void* d_out, int out_size, void* d_ws, size_t ws_size,
                              hipStream_t stream) {
    const float* x     = (const float*)d_in[0];  // [8,512,64]
    const float* theta = (const float*)d_in[1];  // [8]
    const float* Wo    = (const float*)d_in[2];  // [64,64]
    const float* bo    = (const float*)d_in[3];  // [64]
    float* out = (float*)d_out;                  // [8,512,64]
    float* ctx = (float*)d_ws;                   // 1 MB fp32 scratch

    qattn_kernel<<<dim3(64, 8), 256, 0, stream>>>(x, theta, ctx);
    proj_kernel<<<512, 256, 0, stream>>>(ctx, Wo, bo, out);
}